// Round 4
// baseline (410.004 us; speedup 1.0000x reference)
//
#include <hip/hip_runtime.h>

// Dynamic filter layer, 'valid', stride 1:
// out[b,i,j,c] = sum_{di,dj} x[b,i+di,j+dj,c] * flow[b,i,j,di*K+dj]
// B=8, H=W=256, C=64, K=5, Ho=Wo=252. All fp32.
//
// R3: 6x2 register tile per thread (R=6 rows x JR=2 cols):
//  - x float4 loads: 5.0 per output (6 shared columns per sliding row)
//  - flow taps repacked in LDS as [pixel][di][8] (stride 44 words/pixel):
//    each tap row = 1 ds_read_b128 + 1 ds_read_b32, conflict-free banks
//  - __launch_bounds__(256,4): VGPR cap 128, 4 blocks/CU target

constexpr int B  = 8;
constexpr int H  = 256;
constexpr int W  = 256;
constexpr int C  = 64;
constexpr int K  = 5;
constexpr int Ho = H - K + 1;            // 252
constexpr int Wo = W - K + 1;            // 252
constexpr int CQ = C / 4;                // 16 float4 quads per pixel
constexpr int R  = 6;                    // output rows per thread (Ho % R == 0)
constexpr int SEG = Ho / R;              // 42 row segments
constexpr int JR  = 2;                   // output cols per thread
constexpr int JT  = 16 * JR;             // 32 j-pixels per block
constexpr int JB  = (Wo + JT - 1) / JT;  // 8 j blocks (last partial: 28 valid)
constexpr int FP  = 44;                  // words/pixel in LDS: 5 rows x 8 + 4 pad
                                         //  44%4==0 -> 16B-aligned b128 rows
                                         //  jj-lane pixel stride 2*44=88 words
                                         //  -> banks +24 apart: conflict-free

__global__ __launch_bounds__(256, 4) void dfl_kernel(
    const float* __restrict__ x,
    const float* __restrict__ flow,
    float* __restrict__ out)
{
    __shared__ __align__(16) float sf[R * JT * FP];   // 33.8 KB

    const int t   = threadIdx.x;
    const int q   = t & (CQ - 1);         // channel quad 0..15
    const int jj  = t >> 4;               // j-thread 0..15
    const int jl  = jj * JR;              // first local j pixel (0,2,..,30)

    int bid = blockIdx.x;
    const int jb  = bid % JB;  bid /= JB;
    const int seg = bid % SEG; bid /= SEG;
    const int b   = bid;

    const int j0 = jb * JT;
    const int j  = j0 + jl;               // first output col (even)
    const int i0 = seg * R;

    // ---- Stage flow tile: R rows x 32 pixels x 25 taps -> [pix][di][8] ----
    {
        const float* src0 = flow + ((b * Ho + i0) * Wo + j0) * (K * K);
        constexpr int NF = R * JT * K * K;            // 4800
        #pragma unroll
        for (int s0 = 0; s0 < NF; s0 += 256) {
            const int s = s0 + t;
            if (s < NF) {
                const int ii  = s / (JT * K * K);
                const int rem = s - ii * (JT * K * K);
                const int pj  = rem / (K * K);
                const int tap = rem - pj * (K * K);
                const int di  = tap / K;
                const int dj  = tap - di * K;
                if (j0 + pj < Wo)
                    sf[(ii * JT + pj) * FP + di * 8 + dj] =
                        src0[ii * (Wo * K * K) + rem];
            }
        }
    }
    __syncthreads();

    // ---- Compute: vertical sliding window over R+K-1 = 10 x rows ----
    // valid j are even and <= 250; x cols j..j+5 <= 255 always in-bounds.
    const int jc = j < Wo ? j : Wo - 2;   // clamp (keeps cols in-bounds)
    const float4* xq = (const float4*)x + ((b * H + i0) * W + jc) * CQ + q;

    float4 acc[JR][R];
    #pragma unroll
    for (int jr = 0; jr < JR; ++jr)
        #pragma unroll
        for (int ii = 0; ii < R; ++ii)
            acc[jr][ii] = make_float4(0.f, 0.f, 0.f, 0.f);

    #pragma unroll
    for (int r = 0; r < R + K - 1; ++r) {
        float4 xc[K + JR - 1];                         // 6 shared columns
        #pragma unroll
        for (int c = 0; c < K + JR - 1; ++c)
            xc[c] = xq[(r * W + c) * CQ];

        #pragma unroll
        for (int ii = 0; ii < R; ++ii) {
            const int di = r - ii;                     // tap row for output ii
            if (di < 0 || di >= K) continue;           // compile-time resolved
            #pragma unroll
            for (int jr = 0; jr < JR; ++jr) {
                const float* fp = &sf[(ii * JT + jl + jr) * FP + di * 8];
                const float4 fv = *(const float4*)fp;  // taps 0..3 (b128)
                const float  f4 = fp[4];               // tap 4     (b32)
                float4& a = acc[jr][ii];
                a.x += xc[jr + 0].x * fv.x;  a.y += xc[jr + 0].y * fv.x;
                a.z += xc[jr + 0].z * fv.x;  a.w += xc[jr + 0].w * fv.x;
                a.x += xc[jr + 1].x * fv.y;  a.y += xc[jr + 1].y * fv.y;
                a.z += xc[jr + 1].z * fv.y;  a.w += xc[jr + 1].w * fv.y;
                a.x += xc[jr + 2].x * fv.z;  a.y += xc[jr + 2].y * fv.z;
                a.z += xc[jr + 2].z * fv.z;  a.w += xc[jr + 2].w * fv.z;
                a.x += xc[jr + 3].x * fv.w;  a.y += xc[jr + 3].y * fv.w;
                a.z += xc[jr + 3].z * fv.w;  a.w += xc[jr + 3].w * fv.w;
                a.x += xc[jr + 4].x * f4;    a.y += xc[jr + 4].y * f4;
                a.z += xc[jr + 4].z * f4;    a.w += xc[jr + 4].w * f4;
            }
        }
    }

    if (j < Wo) {                                      // j even => j+1 < Wo too
        #pragma unroll
        for (int jr = 0; jr < JR; ++jr) {
            float4* ob = (float4*)out + ((b * Ho + i0) * Wo + j + jr) * CQ + q;
            #pragma unroll
            for (int ii = 0; ii < R; ++ii)
                ob[ii * (Wo * CQ)] = acc[jr][ii];
        }
    }
}

extern "C" void kernel_launch(void* const* d_in, const int* in_sizes, int n_in,
                              void* d_out, int out_size, void* d_ws, size_t ws_size,
                              hipStream_t stream) {
    const float* x    = (const float*)d_in[0];
    const float* flow = (const float*)d_in[1];
    // d_in[2] is ksize (scalar), fixed at 5 — baked in as constexpr.
    float* out = (float*)d_out;

    const int grid = B * SEG * JB;        // 8 * 42 * 8 = 2688 blocks
    dfl_kernel<<<grid, 256, 0, stream>>>(x, flow, out);
}